// Round 9
// baseline (322.853 us; speedup 1.0000x reference)
//
#include <hip/hip_runtime.h>
#include <math.h>

typedef __attribute__((ext_vector_type(8))) short short8;   // 8 bf16 (4 VGPRs)
typedef __attribute__((ext_vector_type(4))) float f32x4;    // MFMA C/D

// fp32 -> bf16 (RNE)
static __device__ __forceinline__ unsigned short f2bf(float f) {
  unsigned int u = __float_as_uint(f);
  u += 0x7FFFu + ((u >> 16) & 1u);
  return (unsigned short)(u >> 16);
}

// async global->LDS, 16B per lane. LDS dest is wave-uniform base + lane*16;
// the GLOBAL address may be arbitrary per lane (exploited to stage
// XOR-swizzled tiles).
static __device__ __forceinline__ void cp16(void* lds, const void* g) {
  __builtin_amdgcn_global_load_lds((const __attribute__((address_space(1))) void*)g,
                                   (__attribute__((address_space(3))) void*)lds,
                                   16, 0, 0);
}

// ---------------------------------------------------------------------------
// Kernel 0: weight prep only (q/k conversion now fused into proj_mfma).
//  blk < 256: W transpose to [n][k] via LDS (both global sides coalesced).
//  else     : Wi pre-swizzle into MFMA B-frag order (K padded 65->96).
// ---------------------------------------------------------------------------
__global__ __launch_bounds__(256) void convert_k(
    const float* __restrict__ Wq, const float* __restrict__ Wk,
    const float* __restrict__ Wv, const float* __restrict__ Wt,
    const float* __restrict__ Wi,
    unsigned short* __restrict__ Wb, unsigned short* __restrict__ WiF)
{
  __shared__ unsigned short tr[64 * 68];
  const int blk = blockIdx.x, tid = threadIdx.x;
  if (blk < 256) {
    int which = blk >> 6, tile = blk & 63;
    int r0 = (tile >> 3) << 6, c0 = (tile & 7) << 6;
    const float* W = (which == 0) ? Wq : (which == 1) ? Wk : (which == 2) ? Wv : Wt;
    const int rr = tid >> 4, cc = (tid & 15) << 2;
#pragma unroll
    for (int u = 0; u < 4; ++u) {
      int r = rr + u * 16;
      float4 v = *(const float4*)(W + (size_t)(r0 + r) * 512 + c0 + cc);
      tr[(cc + 0) * 68 + r] = f2bf(v.x);
      tr[(cc + 1) * 68 + r] = f2bf(v.y);
      tr[(cc + 2) * 68 + r] = f2bf(v.z);
      tr[(cc + 3) * 68 + r] = f2bf(v.w);
    }
    __syncthreads();
    unsigned short* dst = Wb + which * 262144;
#pragma unroll
    for (int u = 0; u < 4; ++u) {
      int c = rr + u * 16;
      ushort4 o = *(const ushort4*)&tr[c * 68 + cc];
      *(ushort4*)(dst + (size_t)(c0 + c) * 512 + r0 + cc) = o;
    }
  } else {
    int e = (blk - 256) * 256 + tid;      // [0, 24576)
    int j = e & 7, ll = (e >> 3) & 63, r = e >> 9;   // r in [0,48)
    int kk = r % 3, nt = r / 3;
    int col = nt * 16 + (ll & 15);
    int k = kk * 32 + (ll >> 4) * 8 + j;
    float val = (k < 64) ? Wi[k * 256 + col] : ((k == 64) ? Wi[16384 + col] : 0.0f);
    WiF[e] = f2bf(val);
  }
}

// ---------------------------------------------------------------------------
// Kernel 1: projections via bf16 MFMA, fused fp32->bf16 conversion for A,
// double-buffered single-barrier k-loop. 128x128 tile, BK=32. A staged via
// register convert + swizzled ds_write; B via swizzled cp16 from Wb.
// Q pre-scaled by 1/sqrt(512); V,T stored transposed via swizzled LDS-bounce.
// ---------------------------------------------------------------------------
__global__ __launch_bounds__(256) void proj_mfma(
    const float* __restrict__ qin, const float* __restrict__ kin,
    const unsigned short* __restrict__ Wb,
    unsigned short* __restrict__ Qg, unsigned short* __restrict__ Kg,
    unsigned short* __restrict__ Vt, unsigned short* __restrict__ Tt)
{
  const int which = blockIdx.z;
  const float* A = (which == 0) ? qin : kin;
  const unsigned short* W = Wb + which * 262144;
  const int row0 = blockIdx.x * 128;
  const int col0 = blockIdx.y * 128;
  const int tid = threadIdx.x;
  const int wv = tid >> 6, l = tid & 63;
  const int quad = l >> 4, lc = l & 15;
  const int wm = wv >> 1, wn = wv & 1;

  __shared__ unsigned short Asm[2][128 * 32];
  __shared__ unsigned short Bsm[2][128 * 32];

  // B cp16 source permute: dest elem-group e: row=e>>2, g=e&3, content g^(row&3)
  const int e2 = tid + 256;
  const int br0 = tid >> 2, bg0 = (tid & 3) ^ (br0 & 3);
  const int br1 = e2 >> 2,  bg1 = (e2 & 3) ^ (br1 & 3);
  // A load/write indices: i = tid + u*256: row = i>>3, c4 = i&7
  f32x4 acc[4][4] = {};

  // prologue: stage k-step 0
  cp16(&Bsm[0][tid * 8], W + (size_t)(col0 + br0) * 512 + bg0 * 8);
  cp16(&Bsm[0][e2 * 8], W + (size_t)(col0 + br1) * 512 + bg1 * 8);
#pragma unroll
  for (int u = 0; u < 4; ++u) {
    int i = tid + u * 256, r = i >> 3, c4 = i & 7;
    float4 v = *(const float4*)(A + (size_t)(row0 + r) * 512 + c4 * 4);
    ushort4 o;
    o.x = f2bf(v.x); o.y = f2bf(v.y); o.z = f2bf(v.z); o.w = f2bf(v.w);
    *(ushort4*)&Asm[0][r * 32 + (((c4 >> 1) ^ (r & 3)) << 3) + ((c4 & 1) << 2)] = o;
  }
  __syncthreads();

  const int xk = lc & 3;                      // frag-read XOR key
  for (int ks = 0; ks < 16; ++ks) {
    const int cur = ks & 1, nxt = cur ^ 1;
    float4 av[4];
    if (ks < 15) {                            // prefetch k-step ks+1
      const int k1 = (ks + 1) << 5;
      cp16(&Bsm[nxt][tid * 8], W + (size_t)(col0 + br0) * 512 + k1 + bg0 * 8);
      cp16(&Bsm[nxt][e2 * 8], W + (size_t)(col0 + br1) * 512 + k1 + bg1 * 8);
#pragma unroll
      for (int u = 0; u < 4; ++u) {
        int i = tid + u * 256, r = i >> 3, c4 = i & 7;
        av[u] = *(const float4*)(A + (size_t)(row0 + r) * 512 + k1 + c4 * 4);
      }
    }
    short8 a[4], b[4];
#pragma unroll
    for (int mi = 0; mi < 4; ++mi)
      a[mi] = *(const short8*)&Asm[cur][(wm * 64 + mi * 16 + lc) * 32 + ((quad ^ xk) << 3)];
#pragma unroll
    for (int nj = 0; nj < 4; ++nj)
      b[nj] = *(const short8*)&Bsm[cur][(wn * 64 + nj * 16 + lc) * 32 + ((quad ^ xk) << 3)];
#pragma unroll
    for (int mi = 0; mi < 4; ++mi)
#pragma unroll
      for (int nj = 0; nj < 4; ++nj)
        acc[mi][nj] = __builtin_amdgcn_mfma_f32_16x16x32_bf16(a[mi], b[nj], acc[mi][nj], 0, 0, 0);
    if (ks < 15) {
#pragma unroll
      for (int u = 0; u < 4; ++u) {
        int i = tid + u * 256, r = i >> 3, c4 = i & 7;
        ushort4 o;
        o.x = f2bf(av[u].x); o.y = f2bf(av[u].y); o.z = f2bf(av[u].z); o.w = f2bf(av[u].w);
        *(ushort4*)&Asm[nxt][r * 32 + (((c4 >> 1) ^ (r & 3)) << 3) + ((c4 & 1) << 2)] = o;
      }
    }
    __syncthreads();
  }

  const int h = (col0 >> 6) + wn;
  const int bidx = row0 >> 9;
  const int hb = h * 16 + bidx;
  if (which < 2) {
    unsigned short* C = (which == 0) ? Qg : Kg;
    const float os = (which == 0) ? 0.044194173824159216f : 1.0f;
#pragma unroll
    for (int mi = 0; mi < 4; ++mi) {
      int sbase = (row0 & 511) + wm * 64 + mi * 16 + quad * 4;
#pragma unroll
      for (int nj = 0; nj < 4; ++nj) {
        size_t base = (size_t)hb * 32768 + (size_t)sbase * 64 + nj * 16 + lc;
#pragma unroll
        for (int reg = 0; reg < 4; ++reg)
          C[base + (size_t)reg * 64] = f2bf(acc[mi][nj][reg] * os);
      }
    }
  } else {
    unsigned short* C = (which == 2) ? Vt : Tt;
    unsigned short* scr = wn ? Bsm[0] : Asm[0];
    const int sb = (row0 & 511) + wm * 64;
    __syncthreads();
#pragma unroll
    for (int round = 0; round < 2; ++round) {
      if (wm == round) {
#pragma unroll
        for (int mi = 0; mi < 4; ++mi)
#pragma unroll
          for (int nj = 0; nj < 4; ++nj)
#pragma unroll
            for (int reg = 0; reg < 4; ++reg) {
              int f = nj * 16 + lc, s = mi * 16 + quad * 4 + reg;
              int g = (s >> 3) ^ (f & 7);
              scr[f * 64 + g * 8 + (s & 7)] = f2bf(acc[mi][nj][reg]);
            }
#pragma unroll
        for (int it = 0; it < 8; ++it) {
          int fl = it * 8 + (l >> 3);
          int gg = (l & 7) ^ (fl & 7);
          short8 v = *(const short8*)&scr[fl * 64 + gg * 8];
          *(short8*)(C + (size_t)hb * 32768 + (size_t)fl * 512 + sb + (l & 7) * 8) = v;
        }
      }
      __syncthreads();
    }
  }
}

// ---------------------------------------------------------------------------
// Kernel 2: fused attention + intensity, 128-row q-blocks, single-barrier
// double-buffered k-loops, register-cached P. Grid (hb=128, y=4),
// qb=[3,2,0,1][y] (XCD-local + CU-balanced). Loop1: P=exp(QK^T) (Q carries
// 1/sqrt(512)), E=P@T, P cached packed-bf16x2 in VGPRs (8kt x 16 = 128 regs).
// Intensity MFMA -> lam (inv-folded); V tile0 + em prefetched under it.
// Loop2: NO score recompute -- unpack cached P, scale by mk=lam.em, P~@V.
// All tiles XOR-swizzled; P bits identical to R7 -> same absmax.
// ---------------------------------------------------------------------------
__global__ __launch_bounds__(256, 2) void attn_fused(
    const unsigned short* __restrict__ Qg, const unsigned short* __restrict__ Kg,
    const unsigned short* __restrict__ Vtg, const unsigned short* __restrict__ Ttg,
    const unsigned short* __restrict__ WiF,
    const float* __restrict__ bi, const float* __restrict__ wim,
    const float* __restrict__ sci, const float* __restrict__ tsp,
    const float* __restrict__ em, const float* __restrict__ queries,
    float* __restrict__ out, float* __restrict__ lamout)
{
  const int hb = blockIdx.x;
  const int y = blockIdx.y;
  const int qb = (y == 0) ? 3 : (y == 1) ? 2 : (y == 2) ? 0 : 1;
  const int q0 = qb << 7;
  const int kts = 2 * qb + 2;                 // k-tiles: {8,6,2,4}
  const int tid = threadIdx.x, wv = tid >> 6, l = tid & 63;
  const int quad = l >> 4, lc = l & 15;
  const int xg = lc & 7;

  __shared__ unsigned short Qs[8192];
  __shared__ unsigned short Ks[2][4096];      // K (loop1) / V (loop2) ping-pong
  __shared__ unsigned short TVs[2][4096];     // T ping-pong (loop1)
  __shared__ unsigned short Wl[4][3072];      // per-wave P / E96: 32 rows x 96
  __shared__ float emS[2][256];

  const int e1 = tid + 256;
  const int sr0 = tid >> 3, sg0 = (tid & 7) ^ (sr0 & 7);
  const int sr1 = e1 >> 3,  sg1 = (e1 & 7) ^ (sr1 & 7);
  const int sqk0 = sr0 * 64 + sg0 * 8,  sqk1 = sr1 * 64 + sg1 * 8;   // [r][64]
  const int stv0 = sr0 * 512 + sg0 * 8, stv1 = sr1 * 512 + sg1 * 8;  // [f][512]

  const unsigned short* KgB = Kg + (size_t)hb * 32768;
  const unsigned short* TgB = Ttg + (size_t)hb * 32768;
  const unsigned short* VgB = Vtg + (size_t)hb * 32768;

  const unsigned short* Qbase = Qg + (size_t)hb * 32768 + q0 * 64;
#pragma unroll
  for (int u = 0; u < 4; ++u) {
    int e = tid + u * 256;
    int r = e >> 3, g = (e & 7) ^ (r & 7);
    cp16(&Qs[e * 8], Qbase + r * 64 + g * 8);
  }
  cp16(&Ks[0][tid * 8], KgB + sqk0);
  cp16(&Ks[0][e1 * 8], KgB + sqk1);
  cp16(&TVs[0][tid * 8], TgB + stv0);
  cp16(&TVs[0][e1 * 8], TgB + stv1);
  __syncthreads();

  short8 aq[2][2];
#pragma unroll
  for (int rt = 0; rt < 2; ++rt)
#pragma unroll
    for (int kk = 0; kk < 2; ++kk)
      aq[rt][kk] = *(const short8*)&Qs[(wv * 32 + rt * 16 + lc) * 64 + ((kk * 4 + quad) ^ xg) * 8];

  f32x4 Eacc[2][4] = {};
  float lsum[2][4] = {};
  unsigned int Pc[8][16];                     // cached P, packed bf16x2

  // ---------------- loop 1: P = exp(QK^T), E = P@T, cache P ----------------
#pragma unroll
  for (int kt = 0; kt < 8; ++kt) {
    if (kt >= kts) continue;                  // uniform per block
    const int cur = kt & 1, nxt = cur ^ 1;
    const int k0 = kt << 6;
    if (kt + 1 < kts) {
      const int k1 = (kt + 1) << 6;
      cp16(&Ks[nxt][tid * 8], KgB + k1 * 64 + sqk0);
      cp16(&Ks[nxt][e1 * 8], KgB + k1 * 64 + sqk1);
      cp16(&TVs[nxt][tid * 8], TgB + k1 + stv0);
      cp16(&TVs[nxt][e1 * 8], TgB + k1 + stv1);
    }
    f32x4 sc[2][4] = {};
#pragma unroll
    for (int kk = 0; kk < 2; ++kk)
#pragma unroll
      for (int nj = 0; nj < 4; ++nj) {
        short8 b = *(const short8*)&Ks[cur][(nj * 16 + lc) * 64 + ((kk * 4 + quad) ^ xg) * 8];
        sc[0][nj] = __builtin_amdgcn_mfma_f32_16x16x32_bf16(aq[0][kk], b, sc[0][nj], 0, 0, 0);
        sc[1][nj] = __builtin_amdgcn_mfma_f32_16x16x32_bf16(aq[1][kk], b, sc[1][nj], 0, 0, 0);
      }
#pragma unroll
    for (int rt = 0; rt < 2; ++rt) {
      const int gq = q0 + wv * 32 + rt * 16 + quad * 4;
#pragma unroll
      for (int nj = 0; nj < 4; ++nj) {
        int col = nj * 16 + lc;
        unsigned short pb[4];
#pragma unroll
        for (int reg = 0; reg < 4; ++reg) {
          float pv = __expf(sc[rt][nj][reg]);
          if (k0 + col > gq + reg) pv = 0.0f;  // causal
          lsum[rt][reg] += pv;
          pb[reg] = f2bf(pv);
          int row = rt * 16 + quad * 4 + reg;
          int gp = (nj * 2 + (lc >> 3)) ^ (row & 7);
          Wl[wv][row * 96 + gp * 8 + (lc & 7)] = pb[reg];
        }
        Pc[kt][(rt * 4 + nj) * 2 + 0] = (unsigned int)pb[0] | ((unsigned int)pb[1] << 16);
        Pc[kt][(rt * 4 + nj) * 2 + 1] = (unsigned int)pb[2] | ((unsigned int)pb[3] << 16);
      }
    }
#pragma unroll
    for (int rt = 0; rt < 2; ++rt)
#pragma unroll
      for (int kk = 0; kk < 2; ++kk) {
        short8 a = *(const short8*)&Wl[wv][(rt * 16 + lc) * 96 + ((kk * 4 + quad) ^ xg) * 8];
#pragma unroll
        for (int fj = 0; fj < 4; ++fj) {
          short8 b = *(const short8*)&TVs[cur][(fj * 16 + lc) * 64 + ((kk * 4 + quad) ^ xg) * 8];
          Eacc[rt][fj] = __builtin_amdgcn_mfma_f32_16x16x32_bf16(a, b, Eacc[rt][fj], 0, 0, 0);
        }
      }
    __syncthreads();
  }

  float inv[2][4];
#pragma unroll
  for (int rt = 0; rt < 2; ++rt)
#pragma unroll
    for (int reg = 0; reg < 4; ++reg) {
      float s = lsum[rt][reg];
#pragma unroll
      for (int off = 1; off < 16; off <<= 1) s += __shfl_xor(s, off);
      inv[rt][reg] = 1.0f / s;
    }

  // prefetch V tile0 + em tile0 (flies under intensity compute)
  cp16(&Ks[0][tid * 8], VgB + stv0);
  cp16(&Ks[0][e1 * 8], VgB + stv1);
  emS[0][tid] = em[(size_t)hb * 2048 + tid];

  // ---------------- E -> wave LDS (A-layout, K=96, swizzled) ----------------
#pragma unroll
  for (int rt = 0; rt < 2; ++rt)
#pragma unroll
    for (int reg = 0; reg < 4; ++reg) {
      int row = rt * 16 + quad * 4 + reg;
      int gq = q0 + wv * 32 + rt * 16 + quad * 4;
      unsigned short* rp = &Wl[wv][row * 96];
#pragma unroll
      for (int fj = 0; fj < 4; ++fj) {
        int gp = (fj * 2 + (lc >> 3)) ^ (row & 7);
        rp[gp * 8 + (lc & 7)] = f2bf(Eacc[rt][fj][reg] * inv[rt][reg]);
      }
      float tsv = (lc == 0) ? tsp[(hb & 15) * 512 + gq + reg] : 0.0f;
      int gt = 8 + ((lc >> 3) ^ (row & 3));
      rp[gt * 8 + (lc & 7)] = f2bf(tsv);
      int gz = 8 + ((2 + (lc >> 3)) ^ (row & 3));
      rp[gz * 8 + (lc & 7)] = 0;
    }

  // ---------------- intensity MFMA (nt-outer) + epilogue ----------------
  float lam4[2][4][4];                        // [rt][reg][m]
#pragma unroll
  for (int rt = 0; rt < 2; ++rt) {
    short8 ia[3];
    ia[0] = *(const short8*)&Wl[wv][(rt * 16 + lc) * 96 + ((0 + quad) ^ xg) * 8];
    ia[1] = *(const short8*)&Wl[wv][(rt * 16 + lc) * 96 + ((4 + quad) ^ xg) * 8];
    ia[2] = *(const short8*)&Wl[wv][(rt * 16 + lc) * 96 + (8 + (quad ^ (lc & 3))) * 8];
    float lac[4][4] = {};
#pragma unroll
    for (int nt = 0; nt < 16; ++nt) {
      f32x4 iacc = {};
#pragma unroll
      for (int kk = 0; kk < 3; ++kk) {
        short8 b = *(const short8*)(WiF + ((nt * 3 + kk) * 64 + l) * 8);
        iacc = __builtin_amdgcn_mfma_f32_16x16x32_bf16(ia[kk], b, iacc, 0, 0, 0);
      }
      float bvv = bi[nt * 16 + lc];
      float wmv = wim[nt * 16 + lc];
#pragma unroll
      for (int reg = 0; reg < 4; ++reg) {
        float mu = 1.0f / (1.0f + __expf(-(iacc[reg] + bvv)));
        lac[reg][nt >> 2] += mu * wmv;
      }
    }
#pragma unroll
    for (int m = 0; m < 4; ++m) {
      float scv = __expf(sci[m]);
#pragma unroll
      for (int reg = 0; reg < 4; ++reg) {
        float s = lac[reg][m];
#pragma unroll
        for (int off = 1; off < 16; off <<= 1) s += __shfl_xor(s, off);
        float z = s / scv;
        float sp = (z > 20.0f) ? z : log1pf(__expf(z));
        lam4[rt][reg][m] = scv * sp;
      }
    }
    if (lc < 4) {
      int gq = q0 + wv * 32 + rt * 16 + quad * 4;
#pragma unroll
      for (int reg = 0; reg < 4; ++reg) {
        float v = (lc == 0) ? lam4[rt][reg][0] : (lc == 1) ? lam4[rt][reg][1]
                : (lc == 2) ? lam4[rt][reg][2] : lam4[rt][reg][3];
        lamout[((size_t)hb * 512 + gq + reg) * 4 + lc] = v;
      }
    }
#pragma unroll
    for (int reg = 0; reg < 4; ++reg)
#pragma unroll
      for (int m = 0; m < 4; ++m)
        lam4[rt][reg][m] *= inv[rt][reg];
  }
  __syncthreads();  // drains V0/em0; all waves past loop1 buffer reads

  // ---------------- loop 2: P~ @ V from cached P (no score recompute) -------
  f32x4 Oacc[2][4] = {};
#pragma unroll
  for (int kt = 0; kt < 8; ++kt) {
    if (kt >= kts) continue;
    const int cur = kt & 1, nxt = cur ^ 1;
    if (kt + 1 < kts) {
      const int k1 = (kt + 1) << 6;
      cp16(&Ks[nxt][tid * 8], VgB + k1 + stv0);
      cp16(&Ks[nxt][e1 * 8], VgB + k1 + stv1);
      emS[nxt][tid] = em[(size_t)hb * 2048 + k1 * 4 + tid];
    }
#pragma unroll
    for (int rt = 0; rt < 2; ++rt) {
#pragma unroll
      for (int nj = 0; nj < 4; ++nj) {
        int col = nj * 16 + lc;
        float4 emv = *(const float4*)&emS[cur][col * 4];
        unsigned int u0 = Pc[kt][(rt * 4 + nj) * 2 + 0];
        unsigned int u1 = Pc[kt][(rt * 4 + nj) * 2 + 1];
        float p[4];
        p[0] = __uint_as_float(u0 << 16);
        p[1] = __uint_as_float(u0 & 0xFFFF0000u);
        p[2] = __uint_as_float(u1 << 16);
        p[3] = __uint_as_float(u1 & 0xFFFF0000u);
#pragma unroll
        for (int reg = 0; reg < 4; ++reg) {
          float mk = lam4[rt][reg][0] * emv.x + lam4[rt][reg][1] * emv.y +
                     lam4[rt][reg][2] * emv.z + lam4[rt][reg][3] * emv.w;
          int row = rt * 16 + quad * 4 + reg;
          int gp = (nj * 2 + (lc >> 3)) ^ (row & 7);
          Wl[wv][row * 96 + gp * 8 + (lc & 7)] = f2bf(p[reg] * mk);
        }
      }
    }
#pragma unroll
    for (int rt = 0; rt < 2; ++rt)
#pragma unroll
      for (int kk = 0; kk < 2; ++kk) {
        short8 a = *(const short8*)&Wl[wv][(rt * 16 + lc) * 96 + ((kk * 4 + quad) ^ xg) * 8];
#pragma unroll
        for (int fj = 0; fj < 4; ++fj) {
          short8 b = *(const short8*)&Ks[cur][(fj * 16 + lc) * 64 + ((kk * 4 + quad) ^ xg) * 8];
          Oacc[rt][fj] = __builtin_amdgcn_mfma_f32_16x16x32_bf16(a, b, Oacc[rt][fj], 0, 0, 0);
        }
      }
    __syncthreads();
  }

  const int h = hb >> 4, bidx = hb & 15;
#pragma unroll
  for (int rt = 0; rt < 2; ++rt) {
    const int gq = q0 + wv * 32 + rt * 16 + quad * 4;
#pragma unroll
    for (int reg = 0; reg < 4; ++reg) {
      size_t o = (size_t)bidx * 262144 + (size_t)(gq + reg) * 512 + h * 64 + lc;
#pragma unroll
      for (int fj = 0; fj < 4; ++fj)
        out[o + fj * 16] = Oacc[rt][fj][reg] + queries[o + fj * 16];
    }
  }
}

// ---------------------------------------------------------------------------
extern "C" void kernel_launch(void* const* d_in, const int* in_sizes, int n_in,
                              void* d_out, int out_size, void* d_ws, size_t ws_size,
                              hipStream_t stream)
{
  (void)in_sizes; (void)n_in; (void)out_size; (void)ws_size;
  const float* queries = (const float*)d_in[0];
  const float* keys    = (const float*)d_in[1];
  const float* tsp     = (const float*)d_in[2];
  // d_in[3] attention_masks: causal tril by construction, applied analytically
  const float* em      = (const float*)d_in[4];
  const float* Wq      = (const float*)d_in[5];
  const float* Wk      = (const float*)d_in[6];
  const float* Wv      = (const float*)d_in[7];
  const float* Wt      = (const float*)d_in[8];
  const float* Wi      = (const float*)d_in[9];
  const float* bi      = (const float*)d_in[10];
  const float* wim     = (const float*)d_in[11];
  const float* sci     = (const float*)d_in[12];
  float* out = (float*)d_out;

  char* w = (char*)d_ws;
  unsigned short* Qg  = (unsigned short*)(w + 0);          // [hb][s][f] bf16 (pre-scaled)
  unsigned short* Kg  = (unsigned short*)(w + 8388608);    // [hb][s][f] bf16
  unsigned short* Vt  = (unsigned short*)(w + 16777216);   // [hb][f][s] bf16
  unsigned short* Tt  = (unsigned short*)(w + 25165824);   // [hb][f][s] bf16
  unsigned short* Wb  = (unsigned short*)(w + 33554432);   // 4x[512][512] transposed
  unsigned short* WiF = (unsigned short*)(w + 35651584);   // frag-ordered Wi

  convert_k<<<352, 256, 0, stream>>>(Wq, Wk, Wv, Wt, Wi, Wb, WiF);
  proj_mfma<<<dim3(64, 4, 4), 256, 0, stream>>>(queries, keys, Wb, Qg, Kg, Vt, Tt);
  attn_fused<<<dim3(128, 4), 256, 0, stream>>>(Qg, Kg, Vt, Tt, WiF, bi, wim, sci,
                                               tsp, em, queries, out,
                                               out + 4194304);
}

// Round 10
// 307.001 us; speedup vs baseline: 1.0516x; 1.0516x over previous
//
#include <hip/hip_runtime.h>
#include <math.h>

typedef __attribute__((ext_vector_type(8))) short short8;   // 8 bf16 (4 VGPRs)
typedef __attribute__((ext_vector_type(4))) float f32x4;    // MFMA C/D

// fp32 -> bf16 (RNE)
static __device__ __forceinline__ unsigned short f2bf(float f) {
  unsigned int u = __float_as_uint(f);
  u += 0x7FFFu + ((u >> 16) & 1u);
  return (unsigned short)(u >> 16);
}

// async global->LDS, 16B per lane. LDS dest is wave-uniform base + lane*16;
// the GLOBAL address may be arbitrary per lane (exploited to stage
// XOR-swizzled tiles).
static __device__ __forceinline__ void cp16(void* lds, const void* g) {
  __builtin_amdgcn_global_load_lds((const __attribute__((address_space(1))) void*)g,
                                   (__attribute__((address_space(3))) void*)lds,
                                   16, 0, 0);
}

// ---------------------------------------------------------------------------
// Kernel 0: weight prep only.
//  blk < 256: W transpose to [n][k] via LDS (both global sides coalesced).
//  else     : Wi pre-swizzle into MFMA B-frag order (K padded 65->96).
// ---------------------------------------------------------------------------
__global__ __launch_bounds__(256) void convert_k(
    const float* __restrict__ Wq, const float* __restrict__ Wk,
    const float* __restrict__ Wv, const float* __restrict__ Wt,
    const float* __restrict__ Wi,
    unsigned short* __restrict__ Wb, unsigned short* __restrict__ WiF)
{
  __shared__ unsigned short tr[64 * 68];
  const int blk = blockIdx.x, tid = threadIdx.x;
  if (blk < 256) {
    int which = blk >> 6, tile = blk & 63;
    int r0 = (tile >> 3) << 6, c0 = (tile & 7) << 6;
    const float* W = (which == 0) ? Wq : (which == 1) ? Wk : (which == 2) ? Wv : Wt;
    const int rr = tid >> 4, cc = (tid & 15) << 2;
#pragma unroll
    for (int u = 0; u < 4; ++u) {
      int r = rr + u * 16;
      float4 v = *(const float4*)(W + (size_t)(r0 + r) * 512 + c0 + cc);
      tr[(cc + 0) * 68 + r] = f2bf(v.x);
      tr[(cc + 1) * 68 + r] = f2bf(v.y);
      tr[(cc + 2) * 68 + r] = f2bf(v.z);
      tr[(cc + 3) * 68 + r] = f2bf(v.w);
    }
    __syncthreads();
    unsigned short* dst = Wb + which * 262144;
#pragma unroll
    for (int u = 0; u < 4; ++u) {
      int c = rr + u * 16;
      ushort4 o = *(const ushort4*)&tr[c * 68 + cc];
      *(ushort4*)(dst + (size_t)(c0 + c) * 512 + r0 + cc) = o;
    }
  } else {
    int e = (blk - 256) * 256 + tid;      // [0, 24576)
    int j = e & 7, ll = (e >> 3) & 63, r = e >> 9;   // r in [0,48)
    int kk = r % 3, nt = r / 3;
    int col = nt * 16 + (ll & 15);
    int k = kk * 32 + (ll >> 4) * 8 + j;
    float val = (k < 64) ? Wi[k * 256 + col] : ((k == 64) ? Wi[16384 + col] : 0.0f);
    WiF[e] = f2bf(val);
  }
}

// ---------------------------------------------------------------------------
// Kernel 1: projections via bf16 MFMA, fused fp32->bf16 conversion for A,
// double-buffered single-barrier k-loop (R8 version — no spills, worked).
// ---------------------------------------------------------------------------
__global__ __launch_bounds__(256) void proj_mfma(
    const float* __restrict__ qin, const float* __restrict__ kin,
    const unsigned short* __restrict__ Wb,
    unsigned short* __restrict__ Qg, unsigned short* __restrict__ Kg,
    unsigned short* __restrict__ Vt, unsigned short* __restrict__ Tt)
{
  const int which = blockIdx.z;
  const float* A = (which == 0) ? qin : kin;
  const unsigned short* W = Wb + which * 262144;
  const int row0 = blockIdx.x * 128;
  const int col0 = blockIdx.y * 128;
  const int tid = threadIdx.x;
  const int wv = tid >> 6, l = tid & 63;
  const int quad = l >> 4, lc = l & 15;
  const int wm = wv >> 1, wn = wv & 1;

  __shared__ unsigned short Asm[2][128 * 32];
  __shared__ unsigned short Bsm[2][128 * 32];

  const int e2 = tid + 256;
  const int br0 = tid >> 2, bg0 = (tid & 3) ^ (br0 & 3);
  const int br1 = e2 >> 2,  bg1 = (e2 & 3) ^ (br1 & 3);
  f32x4 acc[4][4] = {};

  cp16(&Bsm[0][tid * 8], W + (size_t)(col0 + br0) * 512 + bg0 * 8);
  cp16(&Bsm[0][e2 * 8], W + (size_t)(col0 + br1) * 512 + bg1 * 8);
#pragma unroll
  for (int u = 0; u < 4; ++u) {
    int i = tid + u * 256, r = i >> 3, c4 = i & 7;
    float4 v = *(const float4*)(A + (size_t)(row0 + r) * 512 + c4 * 4);
    ushort4 o;
    o.x = f2bf(v.x); o.y = f2bf(v.y); o.z = f2bf(v.z); o.w = f2bf(v.w);
    *(ushort4*)&Asm[0][r * 32 + (((c4 >> 1) ^ (r & 3)) << 3) + ((c4 & 1) << 2)] = o;
  }
  __syncthreads();

  const int xk = lc & 3;                      // frag-read XOR key
  for (int ks = 0; ks < 16; ++ks) {
    const int cur = ks & 1, nxt = cur ^ 1;
    float4 av[4];
    if (ks < 15) {                            // prefetch k-step ks+1
      const int k1 = (ks + 1) << 5;
      cp16(&Bsm[nxt][tid * 8], W + (size_t)(col0 + br0) * 512 + k1 + bg0 * 8);
      cp16(&Bsm[nxt][e2 * 8], W + (size_t)(col0 + br1) * 512 + k1 + bg1 * 8);
#pragma unroll
      for (int u = 0; u < 4; ++u) {
        int i = tid + u * 256, r = i >> 3, c4 = i & 7;
        av[u] = *(const float4*)(A + (size_t)(row0 + r) * 512 + k1 + c4 * 4);
      }
    }
    short8 a[4], b[4];
#pragma unroll
    for (int mi = 0; mi < 4; ++mi)
      a[mi] = *(const short8*)&Asm[cur][(wm * 64 + mi * 16 + lc) * 32 + ((quad ^ xk) << 3)];
#pragma unroll
    for (int nj = 0; nj < 4; ++nj)
      b[nj] = *(const short8*)&Bsm[cur][(wn * 64 + nj * 16 + lc) * 32 + ((quad ^ xk) << 3)];
#pragma unroll
    for (int mi = 0; mi < 4; ++mi)
#pragma unroll
      for (int nj = 0; nj < 4; ++nj)
        acc[mi][nj] = __builtin_amdgcn_mfma_f32_16x16x32_bf16(a[mi], b[nj], acc[mi][nj], 0, 0, 0);
    if (ks < 15) {
#pragma unroll
      for (int u = 0; u < 4; ++u) {
        int i = tid + u * 256, r = i >> 3, c4 = i & 7;
        ushort4 o;
        o.x = f2bf(av[u].x); o.y = f2bf(av[u].y); o.z = f2bf(av[u].z); o.w = f2bf(av[u].w);
        *(ushort4*)&Asm[nxt][r * 32 + (((c4 >> 1) ^ (r & 3)) << 3) + ((c4 & 1) << 2)] = o;
      }
    }
    __syncthreads();
  }

  const int h = (col0 >> 6) + wn;
  const int bidx = row0 >> 9;
  const int hb = h * 16 + bidx;
  if (which < 2) {
    unsigned short* C = (which == 0) ? Qg : Kg;
    const float os = (which == 0) ? 0.044194173824159216f : 1.0f;
#pragma unroll
    for (int mi = 0; mi < 4; ++mi) {
      int sbase = (row0 & 511) + wm * 64 + mi * 16 + quad * 4;
#pragma unroll
      for (int nj = 0; nj < 4; ++nj) {
        size_t base = (size_t)hb * 32768 + (size_t)sbase * 64 + nj * 16 + lc;
#pragma unroll
        for (int reg = 0; reg < 4; ++reg)
          C[base + (size_t)reg * 64] = f2bf(acc[mi][nj][reg] * os);
      }
    }
  } else {
    unsigned short* C = (which == 2) ? Vt : Tt;
    unsigned short* scr = wn ? Bsm[0] : Asm[0];
    const int sb = (row0 & 511) + wm * 64;
    __syncthreads();
#pragma unroll
    for (int round = 0; round < 2; ++round) {
      if (wm == round) {
#pragma unroll
        for (int mi = 0; mi < 4; ++mi)
#pragma unroll
          for (int nj = 0; nj < 4; ++nj)
#pragma unroll
            for (int reg = 0; reg < 4; ++reg) {
              int f = nj * 16 + lc, s = mi * 16 + quad * 4 + reg;
              int g = (s >> 3) ^ (f & 7);
              scr[f * 64 + g * 8 + (s & 7)] = f2bf(acc[mi][nj][reg]);
            }
#pragma unroll
        for (int it = 0; it < 8; ++it) {
          int fl = it * 8 + (l >> 3);
          int gg = (l & 7) ^ (fl & 7);
          short8 v = *(const short8*)&scr[fl * 64 + gg * 8];
          *(short8*)(C + (size_t)hb * 32768 + (size_t)fl * 512 + sb + (l & 7) * 8) = v;
        }
      }
      __syncthreads();
    }
  }
}

// ---------------------------------------------------------------------------
// Kernel 2: fused attention + intensity (R7 version — recompute scores in
// loop2, NO register P-cache; R8's cache spilled to scratch and regressed).
// 128-row q-blocks, single-barrier double-buffered k-loops. Grid (hb=128,y=4),
// qb=[3,2,0,1][y] (XCD-local + CU-balanced). Fixed m=0 softmax (Q pre-scaled).
// ---------------------------------------------------------------------------
__global__ __launch_bounds__(256, 2) void attn_fused(
    const unsigned short* __restrict__ Qg, const unsigned short* __restrict__ Kg,
    const unsigned short* __restrict__ Vtg, const unsigned short* __restrict__ Ttg,
    const unsigned short* __restrict__ WiF,
    const float* __restrict__ bi, const float* __restrict__ wim,
    const float* __restrict__ sci, const float* __restrict__ tsp,
    const float* __restrict__ em, const float* __restrict__ queries,
    float* __restrict__ out, float* __restrict__ lamout)
{
  const int hb = blockIdx.x;
  const int y = blockIdx.y;
  const int qb = (y == 0) ? 3 : (y == 1) ? 2 : (y == 2) ? 0 : 1;
  const int q0 = qb << 7;                     // 128-row q-block
  const int kts = 2 * qb + 2;                 // 64-col k-tiles to process
  const int tid = threadIdx.x, wv = tid >> 6, l = tid & 63;
  const int quad = l >> 4, lc = l & 15;
  const int xg = lc & 7;

  __shared__ unsigned short Qs[8192];         // [128][64] swizzled
  __shared__ unsigned short Ks[2][4096];      // ping-pong K tiles
  __shared__ unsigned short TVs[2][4096];     // ping-pong T (loop1) / V (loop2)
  __shared__ unsigned short Wl[4][3072];      // per-wave P / E96: 32 rows x 96
  __shared__ float emS[2][256];

  const int e1 = tid + 256;
  const int sr0 = tid >> 3, sg0 = (tid & 7) ^ (sr0 & 7);
  const int sr1 = e1 >> 3,  sg1 = (e1 & 7) ^ (sr1 & 7);
  const int sqk0 = sr0 * 64 + sg0 * 8,  sqk1 = sr1 * 64 + sg1 * 8;   // [r][64]
  const int stv0 = sr0 * 512 + sg0 * 8, stv1 = sr1 * 512 + sg1 * 8;  // [f][512]

  const unsigned short* KgB = Kg + (size_t)hb * 32768;
  const unsigned short* TgB = Ttg + (size_t)hb * 32768;
  const unsigned short* VgB = Vtg + (size_t)hb * 32768;

  // stage Q (16 KB) + tile 0 of K,T
  const unsigned short* Qbase = Qg + (size_t)hb * 32768 + q0 * 64;
#pragma unroll
  for (int u = 0; u < 4; ++u) {
    int e = tid + u * 256;
    int r = e >> 3, g = (e & 7) ^ (r & 7);
    cp16(&Qs[e * 8], Qbase + r * 64 + g * 8);
  }
  cp16(&Ks[0][tid * 8], KgB + sqk0);
  cp16(&Ks[0][e1 * 8], KgB + sqk1);
  cp16(&TVs[0][tid * 8], TgB + stv0);
  cp16(&TVs[0][e1 * 8], TgB + stv1);
  __syncthreads();

  // Q A-frags (fixed for whole kernel): rt in {0,1}, kk in {0,1}
  short8 aq[2][2];
#pragma unroll
  for (int rt = 0; rt < 2; ++rt)
#pragma unroll
    for (int kk = 0; kk < 2; ++kk)
      aq[rt][kk] = *(const short8*)&Qs[(wv * 32 + rt * 16 + lc) * 64 + ((kk * 4 + quad) ^ xg) * 8];

  f32x4 Eacc[2][4] = {};
  float lsum[2][4] = {};

  // ---------------- loop 1: P = exp(QK^T), E = P@T ----------------
  for (int kt = 0; kt < kts; ++kt) {
    const int cur = kt & 1, nxt = cur ^ 1;
    const int k0 = kt << 6;
    if (kt + 1 < kts) {                       // prefetch next tile
      const int k1 = (kt + 1) << 6;
      cp16(&Ks[nxt][tid * 8], KgB + k1 * 64 + sqk0);
      cp16(&Ks[nxt][e1 * 8], KgB + k1 * 64 + sqk1);
      cp16(&TVs[nxt][tid * 8], TgB + k1 + stv0);
      cp16(&TVs[nxt][e1 * 8], TgB + k1 + stv1);
    }
    f32x4 sc[2][4] = {};
#pragma unroll
    for (int kk = 0; kk < 2; ++kk)
#pragma unroll
      for (int nj = 0; nj < 4; ++nj) {
        short8 b = *(const short8*)&Ks[cur][(nj * 16 + lc) * 64 + ((kk * 4 + quad) ^ xg) * 8];
        sc[0][nj] = __builtin_amdgcn_mfma_f32_16x16x32_bf16(aq[0][kk], b, sc[0][nj], 0, 0, 0);
        sc[1][nj] = __builtin_amdgcn_mfma_f32_16x16x32_bf16(aq[1][kk], b, sc[1][nj], 0, 0, 0);
      }
#pragma unroll
    for (int rt = 0; rt < 2; ++rt) {
      const int gq = q0 + wv * 32 + rt * 16 + quad * 4;
#pragma unroll
      for (int nj = 0; nj < 4; ++nj) {
        int col = nj * 16 + lc;
#pragma unroll
        for (int reg = 0; reg < 4; ++reg) {
          float pv = __expf(sc[rt][nj][reg]);
          if (k0 + col > gq + reg) pv = 0.0f;  // causal
          lsum[rt][reg] += pv;
          int row = rt * 16 + quad * 4 + reg;
          int gp = (nj * 2 + (lc >> 3)) ^ (row & 7);
          Wl[wv][row * 96 + gp * 8 + (lc & 7)] = f2bf(pv);
        }
      }
    }
    // E += P @ T (Wl wave-private; DS pipe in-order per wave)
#pragma unroll
    for (int rt = 0; rt < 2; ++rt)
#pragma unroll
      for (int kk = 0; kk < 2; ++kk) {
        short8 a = *(const short8*)&Wl[wv][(rt * 16 + lc) * 96 + ((kk * 4 + quad) ^ xg) * 8];
#pragma unroll
        for (int fj = 0; fj < 4; ++fj) {
          short8 b = *(const short8*)&TVs[cur][(fj * 16 + lc) * 64 + ((kk * 4 + quad) ^ xg) * 8];
          Eacc[rt][fj] = __builtin_amdgcn_mfma_f32_16x16x32_bf16(a, b, Eacc[rt][fj], 0, 0, 0);
        }
      }
    __syncthreads();  // drains prefetch; fences cur-buffer reuse
  }

  float inv[2][4];
#pragma unroll
  for (int rt = 0; rt < 2; ++rt)
#pragma unroll
    for (int reg = 0; reg < 4; ++reg) {
      float s = lsum[rt][reg];
#pragma unroll
      for (int off = 1; off < 16; off <<= 1) s += __shfl_xor(s, off);
      inv[rt][reg] = 1.0f / s;
    }

  // ---------------- E -> wave LDS (A-layout, K=96, swizzled) ----------------
#pragma unroll
  for (int rt = 0; rt < 2; ++rt)
#pragma unroll
    for (int reg = 0; reg < 4; ++reg) {
      int row = rt * 16 + quad * 4 + reg;
      int gq = q0 + wv * 32 + rt * 16 + quad * 4;
      unsigned short* rp = &Wl[wv][row * 96];
#pragma unroll
      for (int fj = 0; fj < 4; ++fj) {
        int gp = (fj * 2 + (lc >> 3)) ^ (row & 7);
        rp[gp * 8 + (lc & 7)] = f2bf(Eacc[rt][fj][reg] * inv[rt][reg]);
      }
      float tsv = (lc == 0) ? tsp[(hb & 15) * 512 + gq + reg] : 0.0f;
      int gt = 8 + ((lc >> 3) ^ (row & 3));
      rp[gt * 8 + (lc & 7)] = f2bf(tsv);
      int gz = 8 + ((2 + (lc >> 3)) ^ (row & 3));
      rp[gz * 8 + (lc & 7)] = 0;
    }

  // ---------------- intensity MFMA (nt-outer) + epilogue ----------------
  float lam4[2][4][4];                        // [rt][reg][m]
#pragma unroll
  for (int rt = 0; rt < 2; ++rt) {
    short8 ia[3];
    ia[0] = *(const short8*)&Wl[wv][(rt * 16 + lc) * 96 + ((0 + quad) ^ xg) * 8];
    ia[1] = *(const short8*)&Wl[wv][(rt * 16 + lc) * 96 + ((4 + quad) ^ xg) * 8];
    ia[2] = *(const short8*)&Wl[wv][(rt * 16 + lc) * 96 + (8 + (quad ^ (lc & 3))) * 8];
    float lac[4][4] = {};
#pragma unroll
    for (int nt = 0; nt < 16; ++nt) {
      f32x4 iacc = {};
#pragma unroll
      for (int kk = 0; kk < 3; ++kk) {
        short8 b = *(const short8*)(WiF + ((nt * 3 + kk) * 64 + l) * 8);
        iacc = __builtin_amdgcn_mfma_f32_16x16x32_bf16(ia[kk], b, iacc, 0, 0, 0);
      }
      float bvv = bi[nt * 16 + lc];
      float wmv = wim[nt * 16 + lc];
#pragma unroll
      for (int reg = 0; reg < 4; ++reg) {
        float mu = 1.0f / (1.0f + __expf(-(iacc[reg] + bvv)));
        lac[reg][nt >> 2] += mu * wmv;
      }
    }
#pragma unroll
    for (int m = 0; m < 4; ++m) {
      float scv = __expf(sci[m]);
#pragma unroll
      for (int reg = 0; reg < 4; ++reg) {
        float s = lac[reg][m];
#pragma unroll
        for (int off = 1; off < 16; off <<= 1) s += __shfl_xor(s, off);
        float z = s / scv;
        float sp = (z > 20.0f) ? z : log1pf(__expf(z));
        lam4[rt][reg][m] = scv * sp;
      }
    }
    if (lc < 4) {
      int gq = q0 + wv * 32 + rt * 16 + quad * 4;
#pragma unroll
      for (int reg = 0; reg < 4; ++reg) {
        float v = (lc == 0) ? lam4[rt][reg][0] : (lc == 1) ? lam4[rt][reg][1]
                : (lc == 2) ? lam4[rt][reg][2] : lam4[rt][reg][3];
        lamout[((size_t)hb * 512 + gq + reg) * 4 + lc] = v;
      }
    }
    // fold inv into lam for loop2's P~ scale
#pragma unroll
    for (int reg = 0; reg < 4; ++reg)
#pragma unroll
      for (int m = 0; m < 4; ++m)
        lam4[rt][reg][m] *= inv[rt][reg];
  }

  // ---------------- loop 2: P~ @ V ----------------
  // stage tile 0 of K,V,em (loop1's final barrier fenced all buffers)
  cp16(&Ks[0][tid * 8], KgB + sqk0);
  cp16(&Ks[0][e1 * 8], KgB + sqk1);
  cp16(&TVs[0][tid * 8], VgB + stv0);
  cp16(&TVs[0][e1 * 8], VgB + stv1);
  emS[0][tid] = em[(size_t)hb * 2048 + tid];
  __syncthreads();

  f32x4 Oacc[2][4] = {};
  for (int kt = 0; kt < kts; ++kt) {
    const int cur = kt & 1, nxt = cur ^ 1;
    const int k0 = kt << 6;
    if (kt + 1 < kts) {
      const int k1 = (kt + 1) << 6;
      cp16(&Ks[nxt][tid * 8], KgB + k1 * 64 + sqk0);
      cp16(&Ks[nxt][e1 * 8], KgB + k1 * 64 + sqk1);
      cp16(&TVs[nxt][tid * 8], VgB + k1 + stv0);
      cp16(&TVs[nxt][e1 * 8], VgB + k1 + stv1);
      emS[nxt][tid] = em[(size_t)hb * 2048 + k1 * 4 + tid];
    }
    f32x4 sc[2][4] = {};
#pragma unroll
    for (int kk = 0; kk < 2; ++kk)
#pragma unroll
      for (int nj = 0; nj < 4; ++nj) {
        short8 b = *(const short8*)&Ks[cur][(nj * 16 + lc) * 64 + ((kk * 4 + quad) ^ xg) * 8];
        sc[0][nj] = __builtin_amdgcn_mfma_f32_16x16x32_bf16(aq[0][kk], b, sc[0][nj], 0, 0, 0);
        sc[1][nj] = __builtin_amdgcn_mfma_f32_16x16x32_bf16(aq[1][kk], b, sc[1][nj], 0, 0, 0);
      }
#pragma unroll
    for (int rt = 0; rt < 2; ++rt) {
      const int gq = q0 + wv * 32 + rt * 16 + quad * 4;
#pragma unroll
      for (int nj = 0; nj < 4; ++nj) {
        int col = nj * 16 + lc;
        float4 emv = *(const float4*)&emS[cur][col * 4];
#pragma unroll
        for (int reg = 0; reg < 4; ++reg) {
          float pv = __expf(sc[rt][nj][reg]);
          if (k0 + col > gq + reg) pv = 0.0f;
          float mk = lam4[rt][reg][0] * emv.x + lam4[rt][reg][1] * emv.y +
                     lam4[rt][reg][2] * emv.z + lam4[rt][reg][3] * emv.w;
          int row = rt * 16 + quad * 4 + reg;
          int gp = (nj * 2 + (lc >> 3)) ^ (row & 7);
          Wl[wv][row * 96 + gp * 8 + (lc & 7)] = f2bf(pv * mk);
        }
      }
    }
#pragma unroll
    for (int rt = 0; rt < 2; ++rt)
#pragma unroll
      for (int kk = 0; kk < 2; ++kk) {
        short8 a = *(const short8*)&Wl[wv][(rt * 16 + lc) * 96 + ((kk * 4 + quad) ^ xg) * 8];
#pragma unroll
        for (int fj = 0; fj < 4; ++fj) {
          short8 b = *(const short8*)&TVs[cur][(fj * 16 + lc) * 64 + ((kk * 4 + quad) ^ xg) * 8];
          Oacc[rt][fj] = __builtin_amdgcn_mfma_f32_16x16x32_bf16(a, b, Oacc[rt][fj], 0, 0, 0);
        }
      }
    __syncthreads();
  }

  const int h = hb >> 4, bidx = hb & 15;
#pragma unroll
  for (int rt = 0; rt < 2; ++rt) {
    const int gq = q0 + wv * 32 + rt * 16 + quad * 4;
#pragma unroll
    for (int reg = 0; reg < 4; ++reg) {
      size_t o = (size_t)bidx * 262144 + (size_t)(gq + reg) * 512 + h * 64 + lc;
#pragma unroll
      for (int fj = 0; fj < 4; ++fj)
        out[o + fj * 16] = Oacc[rt][fj][reg] + queries[o + fj * 16];
    }
  }
}

// ---------------------------------------------------------------------------
extern "C" void kernel_launch(void* const* d_in, const int* in_sizes, int n_in,
                              void* d_out, int out_size, void* d_ws, size_t ws_size,
                              hipStream_t stream)
{
  (void)in_sizes; (void)n_in; (void)out_size; (void)ws_size;
  const float* queries = (const float*)d_in[0];
  const float* keys    = (const float*)d_in[1];
  const float* tsp     = (const float*)d_in[2];
  // d_in[3] attention_masks: causal tril by construction, applied analytically
  const float* em      = (const float*)d_in[4];
  const float* Wq      = (const float*)d_in[5];
  const float* Wk      = (const float*)d_in[6];
  const float* Wv      = (const float*)d_in[7];
  const float* Wt      = (const float*)d_in[8];
  const float* Wi      = (const float*)d_in[9];
  const float* bi      = (const float*)d_in[10];
  const float* wim     = (const float*)d_in[11];
  const float* sci     = (const float*)d_in[12];
  float* out = (float*)d_out;

  char* w = (char*)d_ws;
  unsigned short* Qg  = (unsigned short*)(w + 0);          // [hb][s][f] bf16 (pre-scaled)
  unsigned short* Kg  = (unsigned short*)(w + 8388608);    // [hb][s][f] bf16
  unsigned short* Vt  = (unsigned short*)(w + 16777216);   // [hb][f][s] bf16
  unsigned short* Tt  = (unsigned short*)(w + 25165824);   // [hb][f][s] bf16
  unsigned short* Wb  = (unsigned short*)(w + 33554432);   // 4x[512][512] transposed
  unsigned short* WiF = (unsigned short*)(w + 35651584);   // frag-ordered Wi

  convert_k<<<352, 256, 0, stream>>>(Wq, Wk, Wv, Wt, Wi, Wb, WiF);
  proj_mfma<<<dim3(64, 4, 4), 256, 0, stream>>>(queries, keys, Wb, Qg, Kg, Vt, Tt);
  attn_fused<<<dim3(128, 4), 256, 0, stream>>>(Qg, Kg, Vt, Tt, WiF, bi, wim, sci,
                                               tsp, em, queries, out,
                                               out + 4194304);
}